// Round 3
// baseline (2335.461 us; speedup 1.0000x reference)
//
#include <hip/hip_runtime.h>

#define Gn 128
#define Tn 512
#define Sn 24
#define SP 28   // padded LDS row stride (16B-aligned)
#define Mn 4
#define CH 2    // chains per block
#define COVS_BASE (Gn * Tn * Mn)   // 262144

__device__ __forceinline__ float4 ld4(const float* p) {
    return *reinterpret_cast<const float4*>(p);
}
__device__ __forceinline__ void st4(float* p, float4 v) {
    *reinterpret_cast<float4*>(p) = v;
}
__device__ __forceinline__ float dot4(float4 a, float4 b) {
    return a.x*b.x + a.y*b.y + a.z*b.z + a.w*b.w;
}

struct Row24 { float4 v[6]; };

__device__ __forceinline__ Row24 loadRow(const float* p) {
    Row24 r;
#pragma unroll
    for (int i = 0; i < 6; ++i) r.v[i] = ld4(p + 4*i);
    return r;
}

__device__ __forceinline__ float dot24(const Row24& a, const float* b) {
    float4 b0 = ld4(b+0), b1 = ld4(b+4), b2 = ld4(b+8),
           b3 = ld4(b+12), b4 = ld4(b+16), b5 = ld4(b+20);
    float s0 = dot4(a.v[0], b0);
    float s1 = dot4(a.v[1], b1);
    float s2 = dot4(a.v[2], b2);
    float s3 = dot4(a.v[3], b3);
    float s4 = dot4(a.v[4], b4);
    float s5 = dot4(a.v[5], b5);
    return ((s0+s1)+(s2+s3))+(s4+s5);
}

__device__ __forceinline__ float dot24rr(const Row24& a, const Row24& b) {
    float s0 = dot4(a.v[0], b.v[0]);
    float s1 = dot4(a.v[1], b.v[1]);
    float s2 = dot4(a.v[2], b.v[2]);
    float s3 = dot4(a.v[3], b.v[3]);
    float s4 = dot4(a.v[4], b.v[4]);
    float s5 = dot4(a.v[5], b.v[5]);
    return ((s0+s1)+(s2+s3))+(s4+s5);
}

__device__ __forceinline__ float rlane(float v, int l) {
    return __int_as_float(__builtin_amdgcn_readlane(__float_as_int(v), l));
}

// Raw barrier: waits only LDS (lgkmcnt), NOT vmcnt -> prefetch global loads stay
// in flight across the barrier.
__device__ __forceinline__ void barrierLds() {
    asm volatile("s_waitcnt lgkmcnt(0)" ::: "memory");
    __builtin_amdgcn_s_barrier();
    asm volatile("" ::: "memory");
}

extern "C" __global__ void __launch_bounds__(512)
kalman_kernel(const float* __restrict__ y_g, const float* __restrict__ F_g,
              const float* __restrict__ Q_g, const float* __restrict__ H_g,
              const float* __restrict__ R_g, const float* __restrict__ m0_g,
              const float* __restrict__ P0_g, float* __restrict__ out)
{
    const int tid  = threadIdx.x;
    const int wave = tid >> 6;
    const int lane = tid & 63;
    const int c    = wave >> 2;                 // chain within block (0,1)
    const int role = (wave + c) & 3;            // shuffled so each SIMD hosts 2 roles of 2 chains
    const int g    = blockIdx.x * CH + c;
    const int gT   = g * Tn;
    const int sidx = role * 64 + lane;          // 0..255 within this chain

    __shared__ __align__(16) float sP   [CH][Sn*SP];   // covariance (symmetric)
    __shared__ __align__(16) float sFP  [CH][Sn*SP];   // FP = F @ P
    __shared__ __align__(16) float sF   [CH][2][Sn*SP];
    __shared__ __align__(16) float sH   [CH][2][Mn*SP];
    __shared__ __align__(16) float sR   [CH][2][16];
    __shared__ __align__(16) float sy   [CH][2][4];
    __shared__ __align__(16) float sHP  [CH][Mn*SP];   // H@P (4 x 24)
    __shared__ __align__(16) float sW   [CH][Sn*4];    // W = FP@H^T (24 x 4)
    __shared__ __align__(16) float sMean[CH][Sn];
    __shared__ __align__(16) float sFm  [CH][Sn];      // F @ m
    __shared__ __align__(16) float sResid[CH][4];
    __shared__ __align__(16) float sInv [CH][16];      // Sig^-1

    const float4* F4 = reinterpret_cast<const float4*>(F_g);
    const float4* H4 = reinterpret_cast<const float4*>(H_g);
    const float4* R4 = reinterpret_cast<const float4*>(R_g);
    const float4* y4 = reinterpret_cast<const float4*>(y_g);

    // staging: 173 float4 per chain-step: F 144, H 24, R 4, y 1  (Q bypasses LDS)
    auto stage_load = [&](int v, int t) -> float4 {
        if (v < 144)      return F4[(size_t)(gT + t)*144 + v];
        else if (v < 168) return H4[(size_t)(gT + t)*24  + (v-144)];
        else if (v < 172) return R4[(size_t)(gT + t)*4   + (v-168)];
        else              return y4[gT + t];
    };
    auto stage_store = [&](int v, int bb, float4 val) {
        if (v < 144)      { int r = v/6, c2 = (v%6)*4;               st4(&sF[c][bb][r*SP+c2], val); }
        else if (v < 168) { int v2 = v-144; int r = v2/6, c2 = (v2%6)*4; st4(&sH[c][bb][r*SP+c2], val); }
        else if (v < 172) { st4(&sR[c][bb][(v-168)*4], val); }
        else              { st4(&sy[c][bb][0], val); }
    };

    // ---------------- prologue ----------------
    if (sidx < 144) {
        st4(&sP[c][(sidx/6)*SP + (sidx%6)*4], ld4(&P0_g[(size_t)g*Sn*Sn + sidx*4]));
    } else if (sidx < 150) {
        int v = sidx - 144;
        st4(&sMean[c][v*4], ld4(&m0_g[(size_t)g*Sn + v*4]));
    }
    if (sidx < 173) stage_store(sidx, 0, stage_load(sidx, 0));
    __syncthreads();

    // ---------------- hoisted per-lane indices ----------------
    const int ib = lane >> 3, jb = lane & 7;
    const int i0 = 3*ib, j0 = 3*jb;               // 3x3 tiles (role0: FP, role1: A/Pnew)
    const int aH  = lane / 24,      sH_ = lane % 24;       // role2 S1: HP out o=lane
    const int o3  = 64 + lane;
    const int aH3 = o3 / 24,        sH3 = o3 % 24;         // role3 S1 (lane<32)
    const int iW  = lane >> 1,      aW  = (lane & 1)*2;    // role2 S2: W half-rows (lane<48)
    const bool doStage = (sidx < 173);

    float4 pf;
    float qv[9];

    for (int t = 0; t < Tn; ++t) {
        const int  b    = t & 1;
        const int  b1   = b ^ 1;
        const bool last = (t == Tn - 1);

        // prefetch-issue staging for t+1 (in flight across the whole step)
        if (!last && doStage) pf = stage_load(sidx, t+1);
        // Q for THIS step: global -> regs, consumed in S3 (role1 only)
        if (!last && role == 1) {
            const float* Qp = Q_g + (size_t)(gT + t) * 576;
#pragma unroll
            for (int r = 0; r < 3; ++r)
#pragma unroll
                for (int c2 = 0; c2 < 3; ++c2)
                    qv[r*3+c2] = Qp[(i0+r)*24 + j0 + c2];
        }

        // ================= S1: FP (r0) ; Fm (r1) ; HP (r2,r3) ; mu/resid (r3) =================
        if (role == 0) {
            if (!last) {
                Row24 Pj0 = loadRow(&sP[c][(j0+0)*SP]);   // P symmetric: col j == row j
                Row24 Pj1 = loadRow(&sP[c][(j0+1)*SP]);
                Row24 Pj2 = loadRow(&sP[c][(j0+2)*SP]);
#pragma unroll
                for (int r = 0; r < 3; ++r) {
                    Row24 fr = loadRow(&sF[c][b][(i0+r)*SP]);
                    sFP[c][(i0+r)*SP + j0+0] = dot24rr(fr, Pj0);
                    sFP[c][(i0+r)*SP + j0+1] = dot24rr(fr, Pj1);
                    sFP[c][(i0+r)*SP + j0+2] = dot24rr(fr, Pj2);
                }
            }
        } else if (role == 1) {
            if (!last && lane < 24) {   // Fm = F @ m
                Row24 fr = loadRow(&sF[c][b][lane*SP]);
                Row24 mr = loadRow(&sMean[c][0]);
                sFm[c][lane] = dot24rr(fr, mr);
            }
        } else if (role == 2) {         // HP outs 0..63
            Row24 hr = loadRow(&sH[c][b][aH*SP]);
            sHP[c][aH*SP + sH_] = dot24(hr, &sP[c][sH_*SP]);
        } else {                        // role 3
            if (lane < 32) {            // HP outs 64..95
                Row24 hr = loadRow(&sH[c][b][aH3*SP]);
                sHP[c][aH3*SP + sH3] = dot24(hr, &sP[c][sH3*SP]);
            } else if (lane < 36) {     // mu + resid (means output)
                int a = lane - 32;
                Row24 hr = loadRow(&sH[c][b][a*SP]);
                Row24 mr = loadRow(&sMean[c][0]);
                float mu = dot24rr(hr, mr);
                out[(size_t)(gT + t)*4 + a] = mu;
                sResid[c][a] = sy[c][b][a] - mu;
            }
        }
        barrierLds();

        // ================= S2: Sig(+covs) (r3) ; A (r1, regs) ; W (r2) ; Inv (r3) =================
        float sigv = 0.f;
        if (role == 3 && lane < 16) {
            int a = lane >> 2, cc = lane & 3;
            Row24 hpr = loadRow(&sHP[c][a*SP]);
            sigv = dot24(hpr, &sH[c][b][cc*SP]) + sR[c][b][lane];
            out[COVS_BASE + (size_t)(gT + t)*16 + lane] = sigv;   // covs output
        }
        if (last) return;

        float acc[9];
        if (role == 1) {
            Row24 Fj0 = loadRow(&sF[c][b][(j0+0)*SP]);
            Row24 Fj1 = loadRow(&sF[c][b][(j0+1)*SP]);
            Row24 Fj2 = loadRow(&sF[c][b][(j0+2)*SP]);
#pragma unroll
            for (int r = 0; r < 3; ++r) {
                Row24 fp = loadRow(&sFP[c][(i0+r)*SP]);
                acc[r*3+0] = dot24rr(fp, Fj0);
                acc[r*3+1] = dot24rr(fp, Fj1);
                acc[r*3+2] = dot24rr(fp, Fj2);
            }
        } else if (role == 2) {
            if (lane < 48) {   // W: 96 outs, 2 per lane
                Row24 fpw = loadRow(&sFP[c][iW*SP]);
                sW[c][iW*4 + aW]     = dot24(fpw, &sH[c][b][aW*SP]);
                sW[c][iW*4 + aW + 1] = dot24(fpw, &sH[c][b][(aW+1)*SP]);
            }
        } else if (role == 3) {
            // Sig -> uniform regs via intra-wave readlane; full 4x4 inverse uniformly
            float s00 = rlane(sigv, 0), s01 = rlane(sigv, 1), s02 = rlane(sigv, 2), s03 = rlane(sigv, 3);
            float s10 = rlane(sigv, 4), s11 = rlane(sigv, 5), s12 = rlane(sigv, 6), s13 = rlane(sigv, 7);
            float s20 = rlane(sigv, 8), s21 = rlane(sigv, 9), s22 = rlane(sigv,10), s23 = rlane(sigv,11);
            float s30 = rlane(sigv,12), s31 = rlane(sigv,13), s32 = rlane(sigv,14), s33 = rlane(sigv,15);
            float p0 = s00*s11 - s01*s10;
            float p1 = s00*s12 - s02*s10;
            float p2 = s00*s13 - s03*s10;
            float p3 = s01*s12 - s02*s11;
            float p4 = s01*s13 - s03*s11;
            float p5 = s02*s13 - s03*s12;
            float q0 = s20*s31 - s21*s30;
            float q1 = s20*s32 - s22*s30;
            float q2 = s20*s33 - s23*s30;
            float q3 = s21*s32 - s22*s31;
            float q4 = s21*s33 - s23*s31;
            float q5 = s22*s33 - s23*s32;
            float det = p0*q5 - p1*q4 + p2*q3 + p3*q2 - p4*q1 + p5*q0;
            float rd  = 1.0f / det;
            float4 invr0 = make_float4(( s11*q5 - s12*q4 + s13*q3)*rd,
                                       (-s01*q5 + s02*q4 - s03*q3)*rd,
                                       ( s31*p5 - s32*p4 + s33*p3)*rd,
                                       (-s21*p5 + s22*p4 - s23*p3)*rd);
            float4 invr1 = make_float4((-s10*q5 + s12*q2 - s13*q1)*rd,
                                       ( s00*q5 - s02*q2 + s03*q1)*rd,
                                       (-s30*p5 + s32*p2 - s33*p1)*rd,
                                       ( s20*p5 - s22*p2 + s23*p1)*rd);
            float4 invr2 = make_float4(( s10*q4 - s11*q2 + s13*q0)*rd,
                                       (-s00*q4 + s01*q2 - s03*q0)*rd,
                                       ( s30*p4 - s31*p2 + s33*p0)*rd,
                                       (-s20*p4 + s21*p2 - s23*p0)*rd);
            float4 invr3 = make_float4((-s10*q3 + s11*q1 - s12*q0)*rd,
                                       ( s00*q3 - s01*q1 + s02*q0)*rd,
                                       (-s30*p3 + s31*p1 - s32*p0)*rd,
                                       ( s20*p3 - s21*p1 + s22*p0)*rd);
            float4 wv = invr0;
            if (lane == 1) wv = invr1;
            else if (lane == 2) wv = invr2;
            else if (lane == 3) wv = invr3;
            if (lane < 4) st4(&sInv[c][lane*4], wv);
        }
        barrierLds();

        // ================= S3: P⁺ (r1) ; m⁺ (r2) ; land staging (all) =================
        if (role == 1) {
            float4 inv0 = ld4(&sInv[c][0]),  inv1 = ld4(&sInv[c][4]);
            float4 inv2 = ld4(&sInv[c][8]),  inv3 = ld4(&sInv[c][12]);
            float4 wi0 = ld4(&sW[c][(i0+0)*4]);
            float4 wi1 = ld4(&sW[c][(i0+1)*4]);
            float4 wi2 = ld4(&sW[c][(i0+2)*4]);
            float4 wj0 = ld4(&sW[c][(j0+0)*4]);
            float4 wj1 = ld4(&sW[c][(j0+1)*4]);
            float4 wj2 = ld4(&sW[c][(j0+2)*4]);
            float4 X0 = make_float4(dot4(wi0,inv0), dot4(wi0,inv1), dot4(wi0,inv2), dot4(wi0,inv3));
            float4 X1 = make_float4(dot4(wi1,inv0), dot4(wi1,inv1), dot4(wi1,inv2), dot4(wi1,inv3));
            float4 X2 = make_float4(dot4(wi2,inv0), dot4(wi2,inv1), dot4(wi2,inv2), dot4(wi2,inv3));
            sP[c][(i0+0)*SP + j0+0] = acc[0] + qv[0] - dot4(X0, wj0);
            sP[c][(i0+0)*SP + j0+1] = acc[1] + qv[1] - dot4(X0, wj1);
            sP[c][(i0+0)*SP + j0+2] = acc[2] + qv[2] - dot4(X0, wj2);
            sP[c][(i0+1)*SP + j0+0] = acc[3] + qv[3] - dot4(X1, wj0);
            sP[c][(i0+1)*SP + j0+1] = acc[4] + qv[4] - dot4(X1, wj1);
            sP[c][(i0+1)*SP + j0+2] = acc[5] + qv[5] - dot4(X1, wj2);
            sP[c][(i0+2)*SP + j0+0] = acc[6] + qv[6] - dot4(X2, wj0);
            sP[c][(i0+2)*SP + j0+1] = acc[7] + qv[7] - dot4(X2, wj1);
            sP[c][(i0+2)*SP + j0+2] = acc[8] + qv[8] - dot4(X2, wj2);
        } else if (role == 2) {
            if (lane < 24) {   // m⁺ = Fm + (W Inv) resid
                float4 inv0 = ld4(&sInv[c][0]),  inv1 = ld4(&sInv[c][4]);
                float4 inv2 = ld4(&sInv[c][8]),  inv3 = ld4(&sInv[c][12]);
                float4 ws = ld4(&sW[c][lane*4]);
                float4 Xs = make_float4(dot4(ws,inv0), dot4(ws,inv1), dot4(ws,inv2), dot4(ws,inv3));
                sMean[c][lane] = sFm[c][lane] + dot4(Xs, ld4(&sResid[c][0]));
            }
        }
        if (doStage) stage_store(sidx, b1, pf);
        barrierLds();
    }
}

extern "C" void kernel_launch(void* const* d_in, const int* in_sizes, int n_in,
                              void* d_out, int out_size, void* d_ws, size_t ws_size,
                              hipStream_t stream) {
    kalman_kernel<<<Gn/CH, 512, 0, stream>>>(
        (const float*)d_in[0], (const float*)d_in[1], (const float*)d_in[2],
        (const float*)d_in[3], (const float*)d_in[4], (const float*)d_in[5],
        (const float*)d_in[6], (float*)d_out);
}

// Round 5
// 1344.175 us; speedup vs baseline: 1.7375x; 1.7375x over previous
//
#include <hip/hip_runtime.h>

#define Gn 128
#define Tn 512
#define Sn 24
#define SP 28   // padded LDS row stride (16B-aligned)
#define Mn 4
#define COVS_BASE (Gn * Tn * Mn)   // 262144

__device__ __forceinline__ float4 ld4(const float* p) {
    return *reinterpret_cast<const float4*>(p);
}
__device__ __forceinline__ void st4(float* p, float4 v) {
    *reinterpret_cast<float4*>(p) = v;
}
__device__ __forceinline__ float dot4(float4 a, float4 b) {
    return a.x*b.x + a.y*b.y + a.z*b.z + a.w*b.w;
}

struct Row24 { float4 v[6]; };

__device__ __forceinline__ Row24 loadRow(const float* p) {
    Row24 r;
#pragma unroll
    for (int i = 0; i < 6; ++i) r.v[i] = ld4(p + 4*i);
    return r;
}

__device__ __forceinline__ float dot24rr(const Row24& a, const Row24& b) {
    float s0 = dot4(a.v[0], b.v[0]);
    float s1 = dot4(a.v[1], b.v[1]);
    float s2 = dot4(a.v[2], b.v[2]);
    float s3 = dot4(a.v[3], b.v[3]);
    float s4 = dot4(a.v[4], b.v[4]);
    float s5 = dot4(a.v[5], b.v[5]);
    return ((s0+s1)+(s2+s3))+(s4+s5);
}

__device__ __forceinline__ float rlane(float v, int l) {
    return __int_as_float(__builtin_amdgcn_readlane(__float_as_int(v), l));
}

// Raw barrier: waits only LDS (lgkmcnt), NOT vmcnt -> prefetch global loads stay
// in flight across the barrier.
__device__ __forceinline__ void barrierLds() {
    asm volatile("s_waitcnt lgkmcnt(0)" ::: "memory");
    __builtin_amdgcn_s_barrier();
    asm volatile("" ::: "memory");
}

extern "C" __global__ void __launch_bounds__(256, 1)
kalman_kernel(const float* __restrict__ y_g, const float* __restrict__ F_g,
              const float* __restrict__ Q_g, const float* __restrict__ H_g,
              const float* __restrict__ R_g, const float* __restrict__ m0_g,
              const float* __restrict__ P0_g, float* __restrict__ out)
{
    const int tid  = threadIdx.x;
    const int role = tid >> 6;
    const int lane = tid & 63;
    const int g    = blockIdx.x;
    const int gT   = g * Tn;

    __shared__ __align__(16) float sP   [Sn*SP];   // covariance (symmetric)
    __shared__ __align__(16) float sFP  [Sn*SP];   // FP = F @ P
    __shared__ __align__(16) float sF   [2][Sn*SP];
    __shared__ __align__(16) float sH   [2][Mn*SP];
    __shared__ __align__(16) float sR   [2][16];
    __shared__ __align__(16) float sy   [2][4];
    __shared__ __align__(16) float sHP  [Mn*SP];   // H@P (4 x 24)
    __shared__ __align__(16) float sW   [Sn*4];    // W = FP@H^T (24 x 4)
    __shared__ __align__(16) float sMean[Sn];
    __shared__ __align__(16) float sFm  [Sn];      // F @ m
    __shared__ __align__(16) float sResid[4];
    __shared__ __align__(16) float sInv [16];      // Sig^-1

    const float4* F4 = reinterpret_cast<const float4*>(F_g);
    const float4* H4 = reinterpret_cast<const float4*>(H_g);
    const float4* R4 = reinterpret_cast<const float4*>(R_g);
    const float4* y4 = reinterpret_cast<const float4*>(y_g);

    // staging: 173 float4 per step: F 144, H 24, R 4, y 1  (Q bypasses LDS)
    auto stage_load = [&](int v, int t) -> float4 {
        if (v < 144)      return F4[(size_t)(gT + t)*144 + v];
        else if (v < 168) return H4[(size_t)(gT + t)*24  + (v-144)];
        else if (v < 172) return R4[(size_t)(gT + t)*4   + (v-168)];
        else              return y4[gT + t];
    };
    auto stage_store = [&](int v, int bb, float4 val) {
        if (v < 144)      { int r = v/6, c2 = (v%6)*4;               st4(&sF[bb][r*SP+c2], val); }
        else if (v < 168) { int v2 = v-144; int r = v2/6, c2 = (v2%6)*4; st4(&sH[bb][r*SP+c2], val); }
        else if (v < 172) { st4(&sR[bb][(v-168)*4], val); }
        else              { st4(&sy[bb][0], val); }
    };

    // ---------------- prologue ----------------
    if (tid < 144) {
        st4(&sP[(tid/6)*SP + (tid%6)*4], ld4(&P0_g[(size_t)g*Sn*Sn + tid*4]));
    } else if (tid < 150) {
        int v = tid - 144;
        st4(&sMean[v*4], ld4(&m0_g[(size_t)g*Sn + v*4]));
    }
    if (tid < 173) stage_store(tid, 0, stage_load(tid, 0));
    __syncthreads();

    // ---------------- hoisted per-lane indices ----------------
    const int ib = lane >> 3, jb = lane & 7;
    const int i0 = 3*ib, j0 = 3*jb;               // 3x3 tiles (role0: FP, role1: A/Pnew)
    const int aH  = lane / 24,      sH_ = lane % 24;       // role2 S1: HP out o=lane
    const int o3  = 64 + lane;
    const int aH3 = o3 / 24,        sH3 = o3 % 24;         // role3 S1 (lane<32)
    const int iW  = lane >> 1,      aW  = (lane & 1)*2;    // role2 S2: W half-rows (lane<48)
    const bool doStage = (tid < 173);

    float4 pf;
    float qv[9];
    Row24 fj0, fj1, fj2;     // role1: F rows j0..j0+2, preloaded S1, used S2
    Row24 hw0, hw1;          // role2: H rows aW, aW+1, preloaded S1, used S2

    for (int t = 0; t < Tn; ++t) {
        const int  b    = t & 1;
        const int  b1   = b ^ 1;
        const bool last = (t == Tn - 1);

        // global prefetches first: staging for t+1, Q(t) for role1's S3
        if (!last && doStage) pf = stage_load(tid, t+1);
        if (!last && role == 1) {
            const float* Qp = Q_g + (size_t)(gT + t) * 576;
#pragma unroll
            for (int r = 0; r < 3; ++r)
#pragma unroll
            for (int c2 = 0; c2 < 3; ++c2)
                qv[r*3+c2] = Qp[(i0+r)*24 + j0 + c2];
        }

        // ================= S1: FP (r0) ; Fm + preloads (r1) ; HP (r2,r3) ; mu/resid (r3) =================
        if (role == 0) {
            if (!last) {
                // batched operand loads: 6 rows live simultaneously
                Row24 Fi0 = loadRow(&sF[b][(i0+0)*SP]);
                Row24 Fi1 = loadRow(&sF[b][(i0+1)*SP]);
                Row24 Fi2 = loadRow(&sF[b][(i0+2)*SP]);
                Row24 Pj0 = loadRow(&sP[(j0+0)*SP]);   // P symmetric: col j == row j
                Row24 Pj1 = loadRow(&sP[(j0+1)*SP]);
                Row24 Pj2 = loadRow(&sP[(j0+2)*SP]);
                sFP[(i0+0)*SP + j0+0] = dot24rr(Fi0, Pj0);
                sFP[(i0+0)*SP + j0+1] = dot24rr(Fi0, Pj1);
                sFP[(i0+0)*SP + j0+2] = dot24rr(Fi0, Pj2);
                sFP[(i0+1)*SP + j0+0] = dot24rr(Fi1, Pj0);
                sFP[(i0+1)*SP + j0+1] = dot24rr(Fi1, Pj1);
                sFP[(i0+1)*SP + j0+2] = dot24rr(Fi1, Pj2);
                sFP[(i0+2)*SP + j0+0] = dot24rr(Fi2, Pj0);
                sFP[(i0+2)*SP + j0+1] = dot24rr(Fi2, Pj1);
                sFP[(i0+2)*SP + j0+2] = dot24rr(Fi2, Pj2);
            }
        } else if (role == 1) {
            if (!last) {
                // preload S2 operands now (sF[b] stable all step)
                fj0 = loadRow(&sF[b][(j0+0)*SP]);
                fj1 = loadRow(&sF[b][(j0+1)*SP]);
                fj2 = loadRow(&sF[b][(j0+2)*SP]);
                if (lane < 24) {   // Fm = F @ m
                    Row24 fm = loadRow(&sF[b][lane*SP]);
                    Row24 mr = loadRow(&sMean[0]);
                    sFm[lane] = dot24rr(fm, mr);
                }
            }
        } else if (role == 2) {         // HP outs 0..63
            Row24 hr = loadRow(&sH[b][aH*SP]);
            Row24 pr = loadRow(&sP[sH_*SP]);
            if (!last) {                // preload S2 W operands (H rows stable)
                hw0 = loadRow(&sH[b][aW*SP]);
                hw1 = loadRow(&sH[b][(aW+1)*SP]);
            }
            sHP[aH*SP + sH_] = dot24rr(hr, pr);
        } else {                        // role 3
            if (lane < 32) {            // HP outs 64..95
                Row24 hr = loadRow(&sH[b][aH3*SP]);
                Row24 pr = loadRow(&sP[sH3*SP]);
                sHP[aH3*SP + sH3] = dot24rr(hr, pr);
            } else if (lane < 36) {     // mu + resid (means output)
                int a = lane - 32;
                Row24 hr = loadRow(&sH[b][a*SP]);
                Row24 mr = loadRow(&sMean[0]);
                float mu = dot24rr(hr, mr);
                out[(size_t)(gT + t)*4 + a] = mu;
                sResid[a] = sy[b][a] - mu;
            }
        }
        barrierLds();

        // ================= S2: Sig(+covs) + Inv (r3) ; A regs (r1) ; W (r2) =================
        float sigv = 0.f;
        if (role == 3 && lane < 16) {
            int a = lane >> 2, cc = lane & 3;
            Row24 hpr = loadRow(&sHP[a*SP]);
            Row24 hcr = loadRow(&sH[b][cc*SP]);
            sigv = dot24rr(hpr, hcr) + sR[b][lane];
            out[COVS_BASE + (size_t)(gT + t)*16 + lane] = sigv;   // covs output
        }
        if (last) return;

        float acc[9];
        if (role == 1) {
            // batched: 3 FP rows + the 3 preloaded F rows live together
            Row24 FPi0 = loadRow(&sFP[(i0+0)*SP]);
            Row24 FPi1 = loadRow(&sFP[(i0+1)*SP]);
            Row24 FPi2 = loadRow(&sFP[(i0+2)*SP]);
            acc[0] = dot24rr(FPi0, fj0); acc[1] = dot24rr(FPi0, fj1); acc[2] = dot24rr(FPi0, fj2);
            acc[3] = dot24rr(FPi1, fj0); acc[4] = dot24rr(FPi1, fj1); acc[5] = dot24rr(FPi1, fj2);
            acc[6] = dot24rr(FPi2, fj0); acc[7] = dot24rr(FPi2, fj1); acc[8] = dot24rr(FPi2, fj2);
        } else if (role == 2) {
            if (lane < 48) {   // W: 96 outs, 2 per lane (H rows preloaded in S1)
                Row24 fpw = loadRow(&sFP[iW*SP]);
                sW[iW*4 + aW]     = dot24rr(fpw, hw0);
                sW[iW*4 + aW + 1] = dot24rr(fpw, hw1);
            }
        } else if (role == 3) {
            // Sig -> uniform regs via intra-wave readlane; full 4x4 inverse uniformly
            float s00 = rlane(sigv, 0), s01 = rlane(sigv, 1), s02 = rlane(sigv, 2), s03 = rlane(sigv, 3);
            float s10 = rlane(sigv, 4), s11 = rlane(sigv, 5), s12 = rlane(sigv, 6), s13 = rlane(sigv, 7);
            float s20 = rlane(sigv, 8), s21 = rlane(sigv, 9), s22 = rlane(sigv,10), s23 = rlane(sigv,11);
            float s30 = rlane(sigv,12), s31 = rlane(sigv,13), s32 = rlane(sigv,14), s33 = rlane(sigv,15);
            float p0 = s00*s11 - s01*s10;
            float p1 = s00*s12 - s02*s10;
            float p2 = s00*s13 - s03*s10;
            float p3 = s01*s12 - s02*s11;
            float p4 = s01*s13 - s03*s11;
            float p5 = s02*s13 - s03*s12;
            float q0 = s20*s31 - s21*s30;
            float q1 = s20*s32 - s22*s30;
            float q2 = s20*s33 - s23*s30;
            float q3 = s21*s32 - s22*s31;
            float q4 = s21*s33 - s23*s31;
            float q5 = s22*s33 - s23*s32;
            float det = p0*q5 - p1*q4 + p2*q3 + p3*q2 - p4*q1 + p5*q0;
            float rd  = 1.0f / det;
            float4 invr0 = make_float4(( s11*q5 - s12*q4 + s13*q3)*rd,
                                       (-s01*q5 + s02*q4 - s03*q3)*rd,
                                       ( s31*p5 - s32*p4 + s33*p3)*rd,
                                       (-s21*p5 + s22*p4 - s23*p3)*rd);
            float4 invr1 = make_float4((-s10*q5 + s12*q2 - s13*q1)*rd,
                                       ( s00*q5 - s02*q2 + s03*q1)*rd,
                                       (-s30*p5 + s32*p2 - s33*p1)*rd,
                                       ( s20*p5 - s22*p2 + s23*p1)*rd);
            float4 invr2 = make_float4(( s10*q4 - s11*q2 + s13*q0)*rd,
                                       (-s00*q4 + s01*q2 - s03*q0)*rd,
                                       ( s30*p4 - s31*p2 + s33*p0)*rd,
                                       (-s20*p4 + s21*p2 - s23*p0)*rd);
            float4 invr3 = make_float4((-s10*q3 + s11*q1 - s12*q0)*rd,
                                       ( s00*q3 - s01*q1 + s02*q0)*rd,
                                       (-s30*p3 + s31*p1 - s32*p0)*rd,
                                       ( s20*p3 - s21*p1 + s22*p0)*rd);
            float4 wv = invr0;
            if (lane == 1) wv = invr1;
            else if (lane == 2) wv = invr2;
            else if (lane == 3) wv = invr3;
            if (lane < 4) st4(&sInv[lane*4], wv);
        }
        barrierLds();

        // ================= S3: P⁺ (r1) ; m⁺ (r2) ; land staging =================
        if (role == 1) {
            // batched loads: Inv + 6 W rows
            float4 inv0 = ld4(&sInv[0]),  inv1 = ld4(&sInv[4]);
            float4 inv2 = ld4(&sInv[8]),  inv3 = ld4(&sInv[12]);
            float4 wi0 = ld4(&sW[(i0+0)*4]);
            float4 wi1 = ld4(&sW[(i0+1)*4]);
            float4 wi2 = ld4(&sW[(i0+2)*4]);
            float4 wj0 = ld4(&sW[(j0+0)*4]);
            float4 wj1 = ld4(&sW[(j0+1)*4]);
            float4 wj2 = ld4(&sW[(j0+2)*4]);
            float4 X0 = make_float4(dot4(wi0,inv0), dot4(wi0,inv1), dot4(wi0,inv2), dot4(wi0,inv3));
            float4 X1 = make_float4(dot4(wi1,inv0), dot4(wi1,inv1), dot4(wi1,inv2), dot4(wi1,inv3));
            float4 X2 = make_float4(dot4(wi2,inv0), dot4(wi2,inv1), dot4(wi2,inv2), dot4(wi2,inv3));
            sP[(i0+0)*SP + j0+0] = acc[0] + qv[0] - dot4(X0, wj0);
            sP[(i0+0)*SP + j0+1] = acc[1] + qv[1] - dot4(X0, wj1);
            sP[(i0+0)*SP + j0+2] = acc[2] + qv[2] - dot4(X0, wj2);
            sP[(i0+1)*SP + j0+0] = acc[3] + qv[3] - dot4(X1, wj0);
            sP[(i0+1)*SP + j0+1] = acc[4] + qv[4] - dot4(X1, wj1);
            sP[(i0+1)*SP + j0+2] = acc[5] + qv[5] - dot4(X1, wj2);
            sP[(i0+2)*SP + j0+0] = acc[6] + qv[6] - dot4(X2, wj0);
            sP[(i0+2)*SP + j0+1] = acc[7] + qv[7] - dot4(X2, wj1);
            sP[(i0+2)*SP + j0+2] = acc[8] + qv[8] - dot4(X2, wj2);
        } else if (role == 2) {
            if (lane < 24) {   // m⁺ = Fm + (W Inv) resid
                float4 inv0 = ld4(&sInv[0]),  inv1 = ld4(&sInv[4]);
                float4 inv2 = ld4(&sInv[8]),  inv3 = ld4(&sInv[12]);
                float4 ws = ld4(&sW[lane*4]);
                float4 rs = ld4(&sResid[0]);
                float fmv = sFm[lane];
                float4 Xs = make_float4(dot4(ws,inv0), dot4(ws,inv1), dot4(ws,inv2), dot4(ws,inv3));
                sMean[lane] = fmv + dot4(Xs, rs);
            }
        }
        if (doStage) stage_store(tid, b1, pf);
        barrierLds();
    }
}

extern "C" void kernel_launch(void* const* d_in, const int* in_sizes, int n_in,
                              void* d_out, int out_size, void* d_ws, size_t ws_size,
                              hipStream_t stream) {
    kalman_kernel<<<Gn, 256, 0, stream>>>(
        (const float*)d_in[0], (const float*)d_in[1], (const float*)d_in[2],
        (const float*)d_in[3], (const float*)d_in[4], (const float*)d_in[5],
        (const float*)d_in[6], (float*)d_out);
}